// Round 19
// baseline (2357.207 us; speedup 1.0000x reference)
//
#include <hip/hip_runtime.h>
#include <hip/hip_bf16.h>
#include <stdint.h>

typedef __attribute__((ext_vector_type(8))) short bf16x8;
typedef __attribute__((ext_vector_type(4))) float f32x4;
typedef unsigned short u16;
typedef unsigned int u32;

__device__ inline float bf2f(u16 u) {
  unsigned int x = ((unsigned int)u) << 16;
  return __builtin_bit_cast(float, x);
}
__device__ inline u16 f2bf(float f) {
  unsigned int x = __builtin_bit_cast(unsigned int, f);
  unsigned int r = x + 0x7fffu + ((x >> 16) & 1u);
  return (u16)(r >> 16);
}

__device__ inline void load_lds16(const void* g, void* l) {
  __builtin_amdgcn_global_load_lds(
      (const __attribute__((address_space(1))) unsigned int*)g,
      (__attribute__((address_space(3))) unsigned int*)l, 16, 0, 0);
}

template <int N>
__device__ inline void waitv() {
  if constexpr (N == 0) asm volatile("s_waitcnt vmcnt(0)" ::: "memory");
  else if constexpr (N == 1) asm volatile("s_waitcnt vmcnt(1)" ::: "memory");
  else if constexpr (N == 2) asm volatile("s_waitcnt vmcnt(2)" ::: "memory");
  else if constexpr (N == 3) asm volatile("s_waitcnt vmcnt(3)" ::: "memory");
  else if constexpr (N == 4) asm volatile("s_waitcnt vmcnt(4)" ::: "memory");
  else if constexpr (N == 6) asm volatile("s_waitcnt vmcnt(6)" ::: "memory");
}

// swizzled byte offset within a tile of 128-byte rows
#define SWB(r, cb) (((r) << 7) + ((cb) ^ (((r) & 7) << 4)))

// ---------------- embedding + positional encoding ----------------
__global__ __launch_bounds__(256) void embed_kernel(
    const int* __restrict__ x, const float* __restrict__ emb,
    float* __restrict__ h) {
  const int row = blockIdx.x;          // b*1024 + s
  const int s = row & 1023;
  const int tok = x[row];
  const int tid = threadIdx.x;
  const float c = -logf(10000.f) / 768.f;
#pragma unroll
  for (int i = 0; i < 3; ++i) {
    const int d = tid + i * 256;
    const int deven = d & ~1;
    const float ang = (float)s * expf((float)deven * c);
    const float pe = (d & 1) ? cosf(ang) : sinf(ang);
    h[(long)row * 768 + d] = emb[(long)tok * 768 + d] * 27.712812921102035f + pe;
  }
}

// ---------------- layernorm (f32 in -> bf16 out) ----------------
__global__ __launch_bounds__(256) void ln_kernel(
    const float* __restrict__ X, const float* __restrict__ g,
    const float* __restrict__ b, u16* __restrict__ Y) {
  const int row = blockIdx.x;
  const float* xr = X + (long)row * 768;
  const int tid = threadIdx.x;
  float v[3];
  float s = 0.f, sq = 0.f;
#pragma unroll
  for (int i = 0; i < 3; ++i) {
    v[i] = xr[tid + i * 256];
    s += v[i];
    sq += v[i] * v[i];
  }
  __shared__ float red[8];
#pragma unroll
  for (int off = 32; off > 0; off >>= 1) {
    s += __shfl_down(s, off);
    sq += __shfl_down(sq, off);
  }
  const int lane = tid & 63, wid = tid >> 6;
  if (lane == 0) { red[wid] = s; red[wid + 4] = sq; }
  __syncthreads();
  s = red[0] + red[1] + red[2] + red[3];
  sq = red[4] + red[5] + red[6] + red[7];
  const float mean = s * (1.f / 768.f);
  const float var = sq * (1.f / 768.f) - mean * mean;
  const float rs = rsqrtf(var + 1e-5f);
  u16* yr = Y + (long)row * 768;
#pragma unroll
  for (int i = 0; i < 3; ++i) {
    const int d = tid + i * 256;
    yr[d] = f2bf((v[i] - mean) * rs * g[d] + b[d]);
  }
}

// ---------------- f32 (K x N) -> bf16 transposed (Npad x K) ----------------
__global__ void conv_transpose(const float* __restrict__ W, u16* __restrict__ Wt,
                               int K, int N, int Npad) {
  __shared__ float tile[32][33];
  const int n0 = blockIdx.x * 32, k0 = blockIdx.y * 32;
  const int tx = threadIdx.x, ty = threadIdx.y;
  for (int i = ty; i < 32; i += 8) {
    const int n = n0 + tx;
    tile[i][tx] = (n < N) ? W[(long)(k0 + i) * N + n] : 0.f;
  }
  __syncthreads();
  for (int i = ty; i < 32; i += 8) {
    const int n = n0 + i;
    if (n < Npad) Wt[(long)n * K + k0 + tx] = f2bf(tile[tx][i]);
  }
}

// ---- ALL layers' weight conversion in one dispatch: z = layer ----
__global__ void conv_layers(const float* __restrict__ Wq, const float* __restrict__ Wk,
                            const float* __restrict__ Wv, const float* __restrict__ Wo,
                            const float* __restrict__ W1, const float* __restrict__ W2,
                            u16* __restrict__ wbase) {
  __shared__ float tile[32][33];
  const int l = blockIdx.y;
  u16* qkv_t = wbase + (long)l * 7077888;
  u16* wo_t = qkv_t + 1769472;
  u16* w1_t = wo_t + 589824;
  u16* w2_t = w1_t + 2359296;
  const int f = blockIdx.x;
  const float* W;
  u16* dst;
  int n0, k0, ldN, ldK;
  if (f < 2304) {
    const int z = f / 576, rem = f % 576;
    W = ((z == 0) ? Wq : (z == 1) ? Wk : (z == 2) ? Wv : Wo) + l * 589824L;
    dst = (z < 3) ? qkv_t + (long)z * 768 * 768 : wo_t;
    n0 = (rem / 24) * 32; k0 = (rem % 24) * 32; ldN = 768; ldK = 768;
  } else if (f < 4608) {
    const int rem = f - 2304;
    W = W1 + l * 2359296L; dst = w1_t;
    n0 = (rem / 24) * 32; k0 = (rem % 24) * 32; ldN = 3072; ldK = 768;
  } else {
    const int rem = f - 4608;
    W = W2 + l * 2359296L; dst = w2_t;
    n0 = (rem / 96) * 32; k0 = (rem % 96) * 32; ldN = 768; ldK = 3072;
  }
  const int tx = threadIdx.x, ty = threadIdx.y;
  for (int i = ty; i < 32; i += 8)
    tile[i][tx] = W[(long)(k0 + i) * ldN + n0 + tx];
  __syncthreads();
  for (int i = ty; i < 32; i += 8)
    dst[(long)(n0 + i) * ldK + k0 + tx] = f2bf(tile[tx][i]);
}

// ---- all-layer bias concat: bqkv_all[l][2304] = [bq_l, bk_l, bv_l] ----
__global__ __launch_bounds__(256) void bias_all(
    const float* __restrict__ bq, const float* __restrict__ bk,
    const float* __restrict__ bv, float* __restrict__ o) {
  const int idx = blockIdx.x * 256 + threadIdx.x;
  const int l = idx / 2304, r = idx % 2304;
  o[idx] = (r < 768) ? bq[l * 768 + r]
         : (r < 1536) ? bk[l * 768 + r - 768] : bv[l * 768 + r - 1536];
}

// ---- v segment of qkv [2048][2304] -> v_t [2][768][1024] ----
__global__ void transpose_v(const u16* __restrict__ qkv, u16* __restrict__ v_t) {
  __shared__ u16 tile[32][33];
  const int b = blockIdx.z;
  const int c0 = blockIdx.x * 32;
  const int r0 = blockIdx.y * 32;
  const int tx = threadIdx.x, ty = threadIdx.y;
  const u16* in = qkv + (long)b * 1024 * 2304 + 1536;
  for (int i = ty; i < 32; i += 8)
    tile[i][tx] = in[(long)(r0 + i) * 2304 + c0 + tx];
  __syncthreads();
  u16* out = v_t + (long)b * 768 * 1024;
  for (int i = ty; i < 32; i += 8)
    out[(long)(c0 + i) * 1024 + r0 + tx] = tile[tx][i];
}

// ---------------- flash attention (dbuf K/V, causal tile skip, heavy-first) ----
__global__ __launch_bounds__(256) void flash_attn(
    const u16* __restrict__ qkv, const u16* __restrict__ v_t,
    u16* __restrict__ att) {
  __shared__ u16 Qs[4096];
  __shared__ u16 Ks[2][4096];
  __shared__ u16 Vs[2][4096];
  __shared__ u16 Ps[4096];

  const int i = blockIdx.x;
  const int rank = i / 24;
  const int qt = (rank == 0) ? 0 : (rank == 1) ? 15 : (rank - 1);
  const int within = i % 24;
  const int hh = within % 12, b = within / 12;
  const int tid = threadIdx.x, lane = tid & 63, w = tid >> 6;
  const int q = lane & 15, g = lane >> 4;
  const int q0 = qt * 64;
  const int kt0 = (qt < 15) ? qt : 0;

  auto stageKV = [&](int buf, int kt) {
#pragma unroll
    for (int c = 0; c < 2; ++c) {
      const int o = c * 4096 + tid * 16;
      const int r = o >> 7, cb = o & 127;
      const int cbs = cb ^ ((r & 7) << 4);
      load_lds16(qkv + ((long)(b * 1024 + kt * 64 + r)) * 2304 + 768 + hh * 64 + (cbs >> 1),
                 (char*)Ks[buf] + o);
      load_lds16(v_t + ((long)(b * 768 + hh * 64 + r)) * 1024 + kt * 64 + (cbs >> 1),
                 (char*)Vs[buf] + o);
    }
  };

#pragma unroll
  for (int c = 0; c < 2; ++c) {
    const int o = c * 4096 + tid * 16;
    const int r = o >> 7, cb = o & 127;
    const int cbs = cb ^ ((r & 7) << 4);
    load_lds16(qkv + ((long)(b * 1024 + q0 + r)) * 2304 + hh * 64 + (cbs >> 1),
               (char*)Qs + o);
  }
  stageKV(0, kt0);
  waitv<4>();
  __builtin_amdgcn_sched_barrier(0);
  __builtin_amdgcn_s_barrier();
  __builtin_amdgcn_sched_barrier(0);

  bf16x8 qf[2];
#pragma unroll
  for (int c = 0; c < 2; ++c)
    qf[c] = *(const bf16x8*)((char*)Qs + SWB(w * 16 + q, c * 64 + g * 16));

  const int i_lane = q0 + w * 16 + q;
  float m = -1e30f, l = 0.f;
  f32x4 out[4];
#pragma unroll
  for (int t = 0; t < 4; ++t) out[t] = (f32x4){0.f, 0.f, 0.f, 0.f};
  u16* Pw = Ps + w * 1024;

  int cur = 0;
  for (int kt = kt0; kt < 16; ++kt) {
    if (kt + 1 < 16) { stageKV(cur ^ 1, kt + 1); waitv<4>(); }
    else waitv<0>();
    __builtin_amdgcn_sched_barrier(0);
    __builtin_amdgcn_s_barrier();
    __builtin_amdgcn_sched_barrier(0);

    f32x4 acc[4];
#pragma unroll
    for (int t = 0; t < 4; ++t) acc[t] = (f32x4){0.f, 0.f, 0.f, 0.f};
#pragma unroll
    for (int c = 0; c < 2; ++c) {
      const bf16x8 qq = qf[c];
#pragma unroll
      for (int t = 0; t < 4; ++t) {
        const bf16x8 kf = *(const bf16x8*)((char*)Ks[cur] + SWB(t * 16 + q, c * 64 + g * 16));
        acc[t] = __builtin_amdgcn_mfma_f32_16x16x32_bf16(kf, qq, acc[t], 0, 0, 0);
      }
    }

    float s[4][4];
    float tmax = -1e30f;
#pragma unroll
    for (int t = 0; t < 4; ++t)
#pragma unroll
      for (int r = 0; r < 4; ++r) {
        const int j = kt * 64 + t * 16 + g * 4 + r;
        const float v = (j <= i_lane) ? -1e9f : acc[t][r];
        s[t][r] = v;
        tmax = fmaxf(tmax, v);
      }
    tmax = fmaxf(tmax, __shfl_xor(tmax, 16));
    tmax = fmaxf(tmax, __shfl_xor(tmax, 32));
    const float mn = fmaxf(m, tmax);
    const float sf = __expf(m - mn);
    m = mn;
    float rs = 0.f;
    u16 pb[4][4];
#pragma unroll
    for (int t = 0; t < 4; ++t)
#pragma unroll
      for (int r = 0; r < 4; ++r) {
        const float pv = __expf(s[t][r] - mn);
        rs += pv;
        pb[t][r] = f2bf(pv);
      }
    rs += __shfl_xor(rs, 16);
    rs += __shfl_xor(rs, 32);
    l = l * sf + rs;
#pragma unroll
    for (int t = 0; t < 4; ++t)
#pragma unroll
      for (int r = 0; r < 4; ++r) out[t][r] *= sf;

#pragma unroll
    for (int t = 0; t < 4; ++t) {
      uint2 pk;
      pk.x = (u32)pb[t][0] | ((u32)pb[t][1] << 16);
      pk.y = (u32)pb[t][2] | ((u32)pb[t][3] << 16);
      *(uint2*)((char*)Pw + SWB(q, t * 32 + g * 8)) = pk;
    }

#pragma unroll
    for (int c = 0; c < 2; ++c) {
      const bf16x8 pf = *(const bf16x8*)((char*)Pw + SWB(q, c * 64 + g * 16));
#pragma unroll
      for (int t = 0; t < 4; ++t) {
        const bf16x8 vf = *(const bf16x8*)((char*)Vs[cur] + SWB(t * 16 + q, c * 64 + g * 16));
        out[t] = __builtin_amdgcn_mfma_f32_16x16x32_bf16(vf, pf, out[t], 0, 0, 0);
      }
    }
    __builtin_amdgcn_sched_barrier(0);
    __builtin_amdgcn_s_barrier();
    __builtin_amdgcn_sched_barrier(0);
    cur ^= 1;
  }

  const float inv = 1.f / l;
  u16* arow = att + ((long)(b * 1024 + q0 + w * 16 + q)) * 768 + hh * 64;
#pragma unroll
  for (int t = 0; t < 4; ++t) {
    uint2 pk;
    pk.x = (u32)f2bf(out[t][0] * inv) | ((u32)f2bf(out[t][1] * inv) << 16);
    pk.y = (u32)f2bf(out[t][2] * inv) | ((u32)f2bf(out[t][3] * inv) << 16);
    *(uint2*)(arow + t * 16 + g * 4) = pk;
  }
}

// ---------------- per-layer pipelined GEMM: 2-phase/K-tile, counted vmcnt ----
// A-dbuf + B-triple-buf. Steady queue at ph1: [B(t)BC, A(t)AC, B(t+1)BC]
// -> vmcnt(BCALLS) lands B(t)+A(t); last tile vmcnt(0).
template <int BM, int BN, int TH>
__global__ __launch_bounds__(TH, 2) void gemmP(
    const u16* __restrict__ A, const u16* __restrict__ Wt,
    const float* __restrict__ bias, const float* resid,
    float* outF, u16* outB,
    int K, int lda, int ldw, int ldc,
    int Nreal, float scale, int scale_ncols, int relu) {
  constexpr int WN = TH / 128;               // 512->4, 256->2 (WM=2 always)
  constexpr int FM = BM / 32;
  constexpr int FN = BN / (WN * 16);
  constexpr int ACALLS = (BM * 128) / (TH * 16);
  constexpr int BCALLS = (BN * 128) / (TH * 16);

  __shared__ u16 As[2][BM * 64];
  __shared__ u16 Bs[3][BN * 64];

  const int tid = threadIdx.x;
  const int lane = tid & 63;
  const int wid = tid >> 6;
  const int wm = wid / WN, wn = wid % WN;
  const int lrow = lane & 15, kgrp = lane >> 4;

  const long row0 = (long)blockIdx.y * BM;
  const long col0 = (long)blockIdx.x * BN;

  f32x4 acc[FM][FN];
#pragma unroll
  for (int m = 0; m < FM; ++m)
#pragma unroll
    for (int n = 0; n < FN; ++n) acc[m][n] = (f32x4){0.f, 0.f, 0.f, 0.f};

  auto stageA = [&](int buf, int k0, int c) {
    const int o = c * (TH * 16) + tid * 16;
    const int r = o >> 7, cb = o & 127;
    const int cbs = cb ^ ((r & 7) << 4);
    load_lds16(A + (row0 + r) * lda + k0 + (cbs >> 1), (char*)As[buf] + o);
  };
  auto stageB = [&](int buf, int k0, int c) {
    const int o = c * (TH * 16) + tid * 16;
    const int r = o >> 7, cb = o & 127;
    const int cbs = cb ^ ((r & 7) << 4);
    load_lds16(Wt + (col0 + r) * ldw + k0 + (cbs >> 1), (char*)Bs[buf] + o);
  };

  const int T = K >> 6;   // requires T >= 3
#pragma unroll
  for (int c = 0; c < BCALLS; ++c) stageB(0, 0, c);
#pragma unroll
  for (int c = 0; c < ACALLS; ++c) stageA(0, 0, c);
#pragma unroll
  for (int c = 0; c < BCALLS; ++c) stageB(1, 64, c);

  for (int t = 0; t < T; ++t) {
    const int cura = t & 1, nxta = cura ^ 1;
    const int curb = t % 3, nxtb = (t + 2) % 3;
    const int k1 = (t + 1) << 6;
    const int k2 = (t + 2) << 6;
    bf16x8 af[FM], bfr[FN];

    // ---------- phase 1: kk0 ----------
    if (t == T - 1) waitv<0>(); else waitv<BCALLS>();
    __builtin_amdgcn_sched_barrier(0);
    __builtin_amdgcn_s_barrier();
    __builtin_amdgcn_sched_barrier(0);
#pragma unroll
    for (int m = 0; m < FM; ++m)
      af[m] = *(const bf16x8*)((char*)As[cura] + SWB(wm * FM * 16 + m * 16 + lrow, kgrp * 16));
#pragma unroll
    for (int n = 0; n < FN; ++n)
      bfr[n] = *(const bf16x8*)((char*)Bs[curb] + SWB(wn * FN * 16 + n * 16 + lrow, kgrp * 16));
    if (t + 1 < T) {
#pragma unroll
      for (int c = 0; c < ACALLS; ++c) stageA(nxta, k1, c);
    }
    asm volatile("s_waitcnt lgkmcnt(0)" ::: "memory");
    __builtin_amdgcn_sched_barrier(0);
    __builtin_amdgcn_s_setprio(1);
#pragma unroll
    for (int m = 0; m < FM; ++m)
#pragma unroll
      for (int n = 0; n < FN; ++n)
        acc[m][n] = __builtin_amdgcn_mfma_f32_16x16x32_bf16(af[m], bfr[n], acc[m][n], 0, 0, 0);
    __builtin_amdgcn_s_setprio(0);

    // ---------- phase 2: kk1 ----------
    __builtin_amdgcn_s_barrier();
    __builtin_amdgcn_sched_barrier(0);
#pragma unroll
    for (int m = 0; m < FM; ++m)
      af[m] = *(const bf16x8*)((char*)As[cura] + SWB(wm * FM * 16 + m * 16 + lrow, 64 + kgrp * 16));
#pragma unroll
    for (int n = 0; n < FN; ++n)
      bfr[n] = *(const bf16x8*)((char*)Bs[curb] + SWB(wn * FN * 16 + n * 16 + lrow, 64 + kgrp * 16));
    if (t + 2 < T) {
#pragma unroll
      for (int c = 0; c < BCALLS; ++c) stageB(nxtb, k2, c);
    }
    asm volatile("s_waitcnt lgkmcnt(0)" ::: "memory");
    __builtin_amdgcn_sched_barrier(0);
    __builtin_amdgcn_s_setprio(1);
#pragma unroll
    for (int m = 0; m < FM; ++m)
#pragma unroll
      for (int n = 0; n < FN; ++n)
        acc[m][n] = __builtin_amdgcn_mfma_f32_16x16x32_bf16(af[m], bfr[n], acc[m][n], 0, 0, 0);
    __builtin_amdgcn_s_setprio(0);
  }

  // epilogue: r-outer / n-inner so consecutive stores stay within one row
  // (sequential 64B segments -> better write combining)
#pragma unroll
  for (int m = 0; m < FM; ++m) {
    const long rowb = row0 + wm * FM * 16 + m * 16 + kgrp * 4;
#pragma unroll
    for (int r = 0; r < 4; ++r) {
      const long row = rowb + r;
#pragma unroll
      for (int n = 0; n < FN; ++n) {
        const long col = col0 + wn * FN * 16 + n * 16 + lrow;
        if (col < Nreal) {
          const float bb = bias ? bias[col] : 0.f;
          const float sc = (col < scale_ncols) ? scale : 1.f;
          const long idx = row * ldc + col;
          float v = (acc[m][n][r] + bb) * sc;
          if (resid) v += resid[idx];
          if (relu) v = fmaxf(v, 0.f);
          if (outF) outF[idx] = v;
          else outB[idx] = f2bf(v);
        }
      }
    }
  }
}

// ---------------- vocab GEMM: 256x256, 8 waves, 4-phase, A-dbuf + B-TRIPLE-buf ----
__global__ __launch_bounds__(512, 1) void gemm8_vocab(
    const u16* __restrict__ A, const u16* __restrict__ Wt,
    const float* __restrict__ bias, float* __restrict__ outF,
    int K, int lda, int ldw, int ldc, int Nreal) {
  __shared__ u16 As[2][256 * 64];
  __shared__ u16 Bs[3][256 * 64];

  const int tid = threadIdx.x;
  const int lane = tid & 63;
  const int wid = tid >> 6;
  const int wm = wid >> 2, wn = wid & 3;
  const int lrow = lane & 15, kgrp = lane >> 4;

  const int flat = blockIdx.x;
  const int g = flat >> 7, rem = flat & 127;
  const int fullg = gridDim.x >> 7;
  int panel, rb;
  if (g < fullg) { panel = g * 16 + (rem & 15); rb = rem >> 4; }
  else           { panel = fullg * 16 + (rem >> 3); rb = rem & 7; }
  const long row0 = (long)rb * 256;
  const long col0 = (long)panel * 256;

  f32x4 acc[8][4];
#pragma unroll
  for (int m = 0; m < 8; ++m)
#pragma unroll
    for (int n = 0; n < 4; ++n) acc[m][n] = (f32x4){0.f, 0.f, 0.f, 0.f};

  auto stageA = [&](int buf, int k0, int c) {
    const int o = c * 8192 + tid * 16;
    const int r = o >> 7, cb = o & 127;
    const int cbs = cb ^ ((r & 7) << 4);
    load_lds16(A + (row0 + r) * lda + k0 + (cbs >> 1), (char*)As[buf] + o);
  };
  auto stageB = [&](int buf, int k0, int c) {
    const int o = c * 8192 + tid * 16;
    const int r = o >> 7, cb = o & 127;
    const int cbs = cb ^ ((r & 7) << 4);
    load_lds16(Wt + (col0 + r) * ldw + k0 + (cbs >> 1), (char*)Bs[buf] + o);
  };

  const int T = K >> 6;
  stageB(0, 0, 0); stageB(0, 0, 1); stageB(0, 0, 2); stageB(0, 0, 3);
  stageA(0, 0, 0); stageA(0, 0, 2); stageA(0, 0, 1); stageA(0, 0, 3);
  stageB(1, 64, 0); stageB(1, 64, 1); stageB(1, 64, 2); stageB(1, 64, 3);

  for (int t = 0; t < T; ++t) {
    const int cura = t & 1, nxta = cura ^ 1;
    const int curb = t % 3, nxtb = (t + 2) % 3;
    const int k1 = (t + 1) << 6;
    const int k2 = (t + 2) << 6;
    const bool pfA = (t + 1 < T);
    const bool pfB = (t + 2 < T);
    const bool last = (t == T - 1);
    bf16x8 am[4], bn0[4];

    // ---------- phase 1: kk0, m0-3 ----------
    if (last) waitv<2>(); else waitv<6>();
    __builtin_amdgcn_sched_barrier(0);
    __builtin_amdgcn_s_barrier();
    __builtin_amdgcn_sched_barrier(0);
#pragma unroll
    for (int m = 0; m < 4; ++m)
      am[m] = *(const bf16x8*)((char*)As[cura] + SWB(wm * 128 + m * 16 + lrow, kgrp * 16));
#pragma unroll
    for (int n = 0; n < 4; ++n)
      bn0[n] = *(const bf16x8*)((char*)Bs[curb] + SWB(wn * 64 + n * 16 + lrow, kgrp * 16));
    if (pfA) { stageA(nxta, k1, 0); stageA(nxta, k1, 2); }
    asm volatile("s_waitcnt lgkmcnt(0)" ::: "memory");
    __builtin_amdgcn_sched_barrier(0);
    __builtin_amdgcn_s_setprio(1);
#pragma unroll
    for (int m = 0; m < 4; ++m)
#pragma unroll
      for (int n = 0; n < 4; ++n)
        acc[m][n] = __builtin_amdgcn_mfma_f32_16x16x32_bf16(am[m], bn0[n], acc[m][n], 0, 0, 0);
    __builtin_amdgcn_s_setprio(0);

    // ---------- phase 2: kk0, m4-7 ----------
    if (last) waitv<0>(); else waitv<6>();
    __builtin_amdgcn_sched_barrier(0);
    __builtin_amdgcn_s_barrier();
    __builtin_amdgcn_sched_barrier(0);
#pragma unroll
    for (int m = 0; m < 4; ++m)
      am[m] = *(const bf16x8*)((char*)As[cura] + SWB(wm * 128 + (m + 4) * 16 + lrow, kgrp * 16));
    if (pfA) { stageA(nxta, k1, 1); stageA(nxta, k1, 3); }
    asm volatile("s_waitcnt lgkmcnt(0)" ::: "memory");
    __builtin_amdgcn_sched_barrier(0);
    __builtin_amdgcn_s_setprio(1);
#pragma unroll
    for (int m = 0; m < 4; ++m)
#pragma unroll
      for (int n = 0; n < 4; ++n)
        acc[m + 4][n] = __builtin_amdgcn_mfma_f32_16x16x32_bf16(am[m], bn0[n], acc[m + 4][n], 0, 0, 0);
    __builtin_amdgcn_s_setprio(0);

    // ---------- phase 3: kk1, m0-3 ----------
    __builtin_amdgcn_s_barrier();
    __builtin_amdgcn_sched_barrier(0);
#pragma unroll
    for (int m = 0; m < 4; ++m)
      am[m] = *(const bf16x8*)((char*)As[cura] + SWB(wm * 128 + m * 16 + lrow, 64 + kgrp * 16));
#pragma unroll
    for (int n = 0; n < 4; ++n)
      bn0[n] = *(const bf16x8*)((char*)Bs[curb] + SWB(wn * 64 + n * 16 + lrow, 64 + kgrp * 16));
    if (pfB) { stageB(nxtb, k2, 0); stageB(nxtb, k2, 1); }
    asm volatile("s_waitcnt lgkmcnt(0)" ::: "memory");
    __builtin_amdgcn_sched_barrier(0);
    __builtin_amdgcn_s_setprio(1);
#pragma unroll
    for (int m = 0; m < 4; ++m)
#pragma unroll
      for (int n = 0; n < 4; ++n)
        acc[m][n] = __builtin_amdgcn_mfma_f32_16x16x32_bf16(am[m], bn0[n], acc[m][n], 0, 0, 0);
    __builtin_amdgcn_s_setprio(0);

    // ---------- phase 4: kk1, m4-7 ----------
    __builtin_amdgcn_s_barrier();
    __builtin_amdgcn_sched_barrier(0);
#pragma unroll
    for (int m = 0; m < 4; ++m)
      am[m] = *(const bf16x8*)((char*)As[cura] + SWB(wm * 128 + (m + 4) * 16 + lrow, 64 + kgrp * 16));
    if (pfB) { stageB(nxtb, k2, 2); stageB(nxtb, k2, 3); }
    asm volatile("s_waitcnt lgkmcnt(0)" ::: "memory");
    __builtin_amdgcn_sched_barrier(0);
    __builtin_amdgcn_s_setprio(1);
#pragma unroll
    for (int m = 0; m < 4; ++m)
#pragma unroll
      for (int n = 0; n < 4; ++n)
        acc[m + 4][n] = __builtin_amdgcn_mfma_f32_16x16x32_bf16(am[m], bn0[n], acc[m + 4][n], 0, 0, 0);
    __builtin_amdgcn_s_setprio(0);
    __builtin_amdgcn_s_barrier();
  }

  // epilogue: r-outer / n-inner -> consecutive stores walk one row's 64B
  // segments sequentially (write combining) instead of alternating 4 rows.
#pragma unroll
  for (int m = 0; m < 8; ++m) {
    const long rowb = row0 + wm * 128 + m * 16 + kgrp * 4;
#pragma unroll
    for (int r = 0; r < 4; ++r) {
      const long row = rowb + r;
#pragma unroll
      for (int n = 0; n < 4; ++n) {
        const long col = col0 + wn * 64 + n * 16 + lrow;
        if (col < Nreal)
          outF[row * ldc + col] = acc[m][n][r] + bias[col];
      }
    }
  }
}

extern "C" void kernel_launch(void* const* d_in, const int* in_sizes, int n_in,
                              void* d_out, int out_size, void* d_ws, size_t ws_size,
                              hipStream_t stream) {
  const int* x = (const int*)d_in[0];
  const float* tok_emb = (const float*)d_in[1];
  const float* Wq = (const float*)d_in[2];
  const float* bq = (const float*)d_in[3];
  const float* Wk = (const float*)d_in[4];
  const float* bk = (const float*)d_in[5];
  const float* Wv = (const float*)d_in[6];
  const float* bv = (const float*)d_in[7];
  const float* Wo = (const float*)d_in[8];
  const float* bo = (const float*)d_in[9];
  const float* ln1g = (const float*)d_in[10];
  const float* ln1b = (const float*)d_in[11];
  const float* ln2g = (const float*)d_in[12];
  const float* ln2b = (const float*)d_in[13];
  const float* W1 = (const float*)d_in[14];
  const float* b1 = (const float*)d_in[15];
  const float* W2 = (const float*)d_in[16];
  const float* b2 = (const float*)d_in[17];
  const float* lnfg = (const float*)d_in[18];
  const float* lnfb = (const float*)d_in[19];
  const float* Wout = (const float*)d_in[20];
  const float* bout = (const float*)d_in[21];

  char* p = (char*)d_ws;
  auto alloc = [&](size_t bytes) {
    void* r = (void*)p;
    p += (bytes + 255) & ~(size_t)255;
    return r;
  };
  float* h = (float*)alloc(2048L * 768 * 4);
  u16* y = (u16*)alloc(2048L * 768 * 2);
  u16* qkv = (u16*)alloc(2048L * 2304 * 2);
  u16* v_t = (u16*)alloc(2L * 768 * 1024 * 2);
  u16* att = (u16*)alloc(2048L * 768 * 2);
  u16* mid = (u16*)alloc(2048L * 3072 * 2);
  u16* wout_t = (u16*)alloc(50432L * 768 * 2);
  float* bqkv_all = (float*)alloc(12L * 2304 * 4);

  // converted per-layer weights live in d_out (fully overwritten by vocab GEMM)
  u16* wbase = (u16*)d_out;

  const dim3 tb(256);
  const dim3 cb(32, 8);

  embed_kernel<<<2048, tb, 0, stream>>>(x, tok_emb, h);
  bias_all<<<108, tb, 0, stream>>>(bq, bk, bv, bqkv_all);
  conv_transpose<<<dim3(1576, 24), cb, 0, stream>>>(Wout, wout_t, 768, 50257, 50432);
  conv_layers<<<dim3(6912, 12), cb, 0, stream>>>(Wq, Wk, Wv, Wo, W1, W2, wbase);

  for (int l = 0; l < 12; ++l) {
    u16* wl = wbase + (long)l * 7077888;
    u16* qkvt_l = wl;
    u16* wot_l = wl + 1769472;
    u16* w1t_l = wot_l + 589824;
    u16* w2t_l = w1t_l + 2359296;

    ln_kernel<<<2048, tb, 0, stream>>>(h, ln1g + l * 768, ln1b + l * 768, y);

    // fused QKV: qkv = (y @ [Wq|Wk|Wv] + bqkv), q cols scaled 1/8 (128x128 tiles)
    gemmP<128, 128, 512><<<dim3(18, 16), dim3(512), 0, stream>>>(
        y, qkvt_l, bqkv_all + l * 2304, nullptr, nullptr, qkv,
        768, 768, 768, 2304, 2304, 0.125f, 768, 0);

    transpose_v<<<dim3(24, 32, 2), cb, 0, stream>>>(qkv, v_t);

    flash_attn<<<dim3(384), tb, 0, stream>>>(qkv, v_t, att);

    // h += att @ Wo + bo
    gemmP<64, 64, 256><<<dim3(12, 32), tb, 0, stream>>>(
        att, wot_l, bo + l * 768, h, h, nullptr,
        768, 768, 768, 768, 768, 1.f, 0, 0);

    ln_kernel<<<2048, tb, 0, stream>>>(h, ln2g + l * 768, ln2b + l * 768, y);

    // mid = relu(y @ W1 + b1)  (128x128 tiles)
    gemmP<128, 128, 512><<<dim3(24, 16), dim3(512), 0, stream>>>(
        y, w1t_l, b1 + l * 3072, nullptr, nullptr, mid,
        768, 768, 768, 3072, 3072, 1.f, 0, 1);

    // h += mid @ W2 + b2
    gemmP<64, 64, 256><<<dim3(12, 32), tb, 0, stream>>>(
        mid, w2t_l, b2 + l * 768, h, h, nullptr,
        3072, 3072, 3072, 768, 768, 1.f, 0, 0);
  }

  ln_kernel<<<2048, tb, 0, stream>>>(h, lnfg, lnfb, y);

  // logits = y @ Wout + bout — 4-phase 256x256, A-dbuf + B-triple-buf
  gemm8_vocab<<<dim3(1576), dim3(512), 0, stream>>>(
      y, wout_t, bout, (float*)d_out, 768, 768, 768, 50257, 50257);
}

// Round 20
// 2142.064 us; speedup vs baseline: 1.1004x; 1.1004x over previous
//
#include <hip/hip_runtime.h>
#include <hip/hip_bf16.h>
#include <stdint.h>

typedef __attribute__((ext_vector_type(8))) short bf16x8;
typedef __attribute__((ext_vector_type(4))) float f32x4;
typedef unsigned short u16;
typedef unsigned int u32;

__device__ inline float bf2f(u16 u) {
  unsigned int x = ((unsigned int)u) << 16;
  return __builtin_bit_cast(float, x);
}
__device__ inline u16 f2bf(float f) {
  unsigned int x = __builtin_bit_cast(unsigned int, f);
  unsigned int r = x + 0x7fffu + ((x >> 16) & 1u);
  return (u16)(r >> 16);
}

__device__ inline void load_lds16(const void* g, void* l) {
  __builtin_amdgcn_global_load_lds(
      (const __attribute__((address_space(1))) unsigned int*)g,
      (__attribute__((address_space(3))) unsigned int*)l, 16, 0, 0);
}

template <int N>
__device__ inline void waitv() {
  if constexpr (N == 0) asm volatile("s_waitcnt vmcnt(0)" ::: "memory");
  else if constexpr (N == 1) asm volatile("s_waitcnt vmcnt(1)" ::: "memory");
  else if constexpr (N == 2) asm volatile("s_waitcnt vmcnt(2)" ::: "memory");
  else if constexpr (N == 3) asm volatile("s_waitcnt vmcnt(3)" ::: "memory");
  else if constexpr (N == 4) asm volatile("s_waitcnt vmcnt(4)" ::: "memory");
  else if constexpr (N == 6) asm volatile("s_waitcnt vmcnt(6)" ::: "memory");
}

// swizzled byte offset within a tile of 128-byte rows
#define SWB(r, cb) (((r) << 7) + ((cb) ^ (((r) & 7) << 4)))

// ---------------- embedding + positional encoding ----------------
__global__ __launch_bounds__(256) void embed_kernel(
    const int* __restrict__ x, const float* __restrict__ emb,
    float* __restrict__ h) {
  const int row = blockIdx.x;          // b*1024 + s
  const int s = row & 1023;
  const int tok = x[row];
  const int tid = threadIdx.x;
  const float c = -logf(10000.f) / 768.f;
#pragma unroll
  for (int i = 0; i < 3; ++i) {
    const int d = tid + i * 256;
    const int deven = d & ~1;
    const float ang = (float)s * expf((float)deven * c);
    const float pe = (d & 1) ? cosf(ang) : sinf(ang);
    h[(long)row * 768 + d] = emb[(long)tok * 768 + d] * 27.712812921102035f + pe;
  }
}

// ---------------- layernorm (f32 in -> bf16 out) ----------------
__global__ __launch_bounds__(256) void ln_kernel(
    const float* __restrict__ X, const float* __restrict__ g,
    const float* __restrict__ b, u16* __restrict__ Y) {
  const int row = blockIdx.x;
  const float* xr = X + (long)row * 768;
  const int tid = threadIdx.x;
  float v[3];
  float s = 0.f, sq = 0.f;
#pragma unroll
  for (int i = 0; i < 3; ++i) {
    v[i] = xr[tid + i * 256];
    s += v[i];
    sq += v[i] * v[i];
  }
  __shared__ float red[8];
#pragma unroll
  for (int off = 32; off > 0; off >>= 1) {
    s += __shfl_down(s, off);
    sq += __shfl_down(sq, off);
  }
  const int lane = tid & 63, wid = tid >> 6;
  if (lane == 0) { red[wid] = s; red[wid + 4] = sq; }
  __syncthreads();
  s = red[0] + red[1] + red[2] + red[3];
  sq = red[4] + red[5] + red[6] + red[7];
  const float mean = s * (1.f / 768.f);
  const float var = sq * (1.f / 768.f) - mean * mean;
  const float rs = rsqrtf(var + 1e-5f);
  u16* yr = Y + (long)row * 768;
#pragma unroll
  for (int i = 0; i < 3; ++i) {
    const int d = tid + i * 256;
    yr[d] = f2bf((v[i] - mean) * rs * g[d] + b[d]);
  }
}

// ---------------- f32 (K x N) -> bf16 transposed (Npad x K) ----------------
__global__ void conv_transpose(const float* __restrict__ W, u16* __restrict__ Wt,
                               int K, int N, int Npad) {
  __shared__ float tile[32][33];
  const int n0 = blockIdx.x * 32, k0 = blockIdx.y * 32;
  const int tx = threadIdx.x, ty = threadIdx.y;
  for (int i = ty; i < 32; i += 8) {
    const int n = n0 + tx;
    tile[i][tx] = (n < N) ? W[(long)(k0 + i) * N + n] : 0.f;
  }
  __syncthreads();
  for (int i = ty; i < 32; i += 8) {
    const int n = n0 + i;
    if (n < Npad) Wt[(long)n * K + k0 + tx] = f2bf(tile[tx][i]);
  }
}

// ---- ALL layers' weight conversion in one dispatch: z = layer ----
__global__ void conv_layers(const float* __restrict__ Wq, const float* __restrict__ Wk,
                            const float* __restrict__ Wv, const float* __restrict__ Wo,
                            const float* __restrict__ W1, const float* __restrict__ W2,
                            u16* __restrict__ wbase) {
  __shared__ float tile[32][33];
  const int l = blockIdx.y;
  u16* qkv_t = wbase + (long)l * 7077888;
  u16* wo_t = qkv_t + 1769472;
  u16* w1_t = wo_t + 589824;
  u16* w2_t = w1_t + 2359296;
  const int f = blockIdx.x;
  const float* W;
  u16* dst;
  int n0, k0, ldN, ldK;
  if (f < 2304) {
    const int z = f / 576, rem = f % 576;
    W = ((z == 0) ? Wq : (z == 1) ? Wk : (z == 2) ? Wv : Wo) + l * 589824L;
    dst = (z < 3) ? qkv_t + (long)z * 768 * 768 : wo_t;
    n0 = (rem / 24) * 32; k0 = (rem % 24) * 32; ldN = 768; ldK = 768;
  } else if (f < 4608) {
    const int rem = f - 2304;
    W = W1 + l * 2359296L; dst = w1_t;
    n0 = (rem / 24) * 32; k0 = (rem % 24) * 32; ldN = 3072; ldK = 768;
  } else {
    const int rem = f - 4608;
    W = W2 + l * 2359296L; dst = w2_t;
    n0 = (rem / 96) * 32; k0 = (rem % 96) * 32; ldN = 768; ldK = 3072;
  }
  const int tx = threadIdx.x, ty = threadIdx.y;
  for (int i = ty; i < 32; i += 8)
    tile[i][tx] = W[(long)(k0 + i) * ldN + n0 + tx];
  __syncthreads();
  for (int i = ty; i < 32; i += 8)
    dst[(long)(n0 + i) * ldK + k0 + tx] = f2bf(tile[tx][i]);
}

// ---- all-layer bias concat: bqkv_all[l][2304] = [bq_l, bk_l, bv_l] ----
__global__ __launch_bounds__(256) void bias_all(
    const float* __restrict__ bq, const float* __restrict__ bk,
    const float* __restrict__ bv, float* __restrict__ o) {
  const int idx = blockIdx.x * 256 + threadIdx.x;
  const int l = idx / 2304, r = idx % 2304;
  o[idx] = (r < 768) ? bq[l * 768 + r]
         : (r < 1536) ? bk[l * 768 + r - 768] : bv[l * 768 + r - 1536];
}

// ---- v segment of qkv [2048][2304] -> v_t [2][768][1024] ----
__global__ void transpose_v(const u16* __restrict__ qkv, u16* __restrict__ v_t) {
  __shared__ u16 tile[32][33];
  const int b = blockIdx.z;
  const int c0 = blockIdx.x * 32;
  const int r0 = blockIdx.y * 32;
  const int tx = threadIdx.x, ty = threadIdx.y;
  const u16* in = qkv + (long)b * 1024 * 2304 + 1536;
  for (int i = ty; i < 32; i += 8)
    tile[i][tx] = in[(long)(r0 + i) * 2304 + c0 + tx];
  __syncthreads();
  u16* out = v_t + (long)b * 768 * 1024;
  for (int i = ty; i < 32; i += 8)
    out[(long)(c0 + i) * 1024 + r0 + tx] = tile[tx][i];
}

// ---------------- flash attention (dbuf K/V, causal tile skip, heavy-first) ----
__global__ __launch_bounds__(256) void flash_attn(
    const u16* __restrict__ qkv, const u16* __restrict__ v_t,
    u16* __restrict__ att) {
  __shared__ u16 Qs[4096];
  __shared__ u16 Ks[2][4096];
  __shared__ u16 Vs[2][4096];
  __shared__ u16 Ps[4096];

  const int i = blockIdx.x;
  const int rank = i / 24;
  const int qt = (rank == 0) ? 0 : (rank == 1) ? 15 : (rank - 1);
  const int within = i % 24;
  const int hh = within % 12, b = within / 12;
  const int tid = threadIdx.x, lane = tid & 63, w = tid >> 6;
  const int q = lane & 15, g = lane >> 4;
  const int q0 = qt * 64;
  const int kt0 = (qt < 15) ? qt : 0;

  auto stageKV = [&](int buf, int kt) {
#pragma unroll
    for (int c = 0; c < 2; ++c) {
      const int o = c * 4096 + tid * 16;
      const int r = o >> 7, cb = o & 127;
      const int cbs = cb ^ ((r & 7) << 4);
      load_lds16(qkv + ((long)(b * 1024 + kt * 64 + r)) * 2304 + 768 + hh * 64 + (cbs >> 1),
                 (char*)Ks[buf] + o);
      load_lds16(v_t + ((long)(b * 768 + hh * 64 + r)) * 1024 + kt * 64 + (cbs >> 1),
                 (char*)Vs[buf] + o);
    }
  };

#pragma unroll
  for (int c = 0; c < 2; ++c) {
    const int o = c * 4096 + tid * 16;
    const int r = o >> 7, cb = o & 127;
    const int cbs = cb ^ ((r & 7) << 4);
    load_lds16(qkv + ((long)(b * 1024 + q0 + r)) * 2304 + hh * 64 + (cbs >> 1),
               (char*)Qs + o);
  }
  stageKV(0, kt0);
  waitv<4>();
  __builtin_amdgcn_sched_barrier(0);
  __builtin_amdgcn_s_barrier();
  __builtin_amdgcn_sched_barrier(0);

  bf16x8 qf[2];
#pragma unroll
  for (int c = 0; c < 2; ++c)
    qf[c] = *(const bf16x8*)((char*)Qs + SWB(w * 16 + q, c * 64 + g * 16));

  const int i_lane = q0 + w * 16 + q;
  float m = -1e30f, l = 0.f;
  f32x4 out[4];
#pragma unroll
  for (int t = 0; t < 4; ++t) out[t] = (f32x4){0.f, 0.f, 0.f, 0.f};
  u16* Pw = Ps + w * 1024;

  int cur = 0;
  for (int kt = kt0; kt < 16; ++kt) {
    if (kt + 1 < 16) { stageKV(cur ^ 1, kt + 1); waitv<4>(); }
    else waitv<0>();
    __builtin_amdgcn_sched_barrier(0);
    __builtin_amdgcn_s_barrier();
    __builtin_amdgcn_sched_barrier(0);

    f32x4 acc[4];
#pragma unroll
    for (int t = 0; t < 4; ++t) acc[t] = (f32x4){0.f, 0.f, 0.f, 0.f};
#pragma unroll
    for (int c = 0; c < 2; ++c) {
      const bf16x8 qq = qf[c];
#pragma unroll
      for (int t = 0; t < 4; ++t) {
        const bf16x8 kf = *(const bf16x8*)((char*)Ks[cur] + SWB(t * 16 + q, c * 64 + g * 16));
        acc[t] = __builtin_amdgcn_mfma_f32_16x16x32_bf16(kf, qq, acc[t], 0, 0, 0);
      }
    }

    float s[4][4];
    float tmax = -1e30f;
#pragma unroll
    for (int t = 0; t < 4; ++t)
#pragma unroll
      for (int r = 0; r < 4; ++r) {
        const int j = kt * 64 + t * 16 + g * 4 + r;
        const float v = (j <= i_lane) ? -1e9f : acc[t][r];
        s[t][r] = v;
        tmax = fmaxf(tmax, v);
      }
    tmax = fmaxf(tmax, __shfl_xor(tmax, 16));
    tmax = fmaxf(tmax, __shfl_xor(tmax, 32));
    const float mn = fmaxf(m, tmax);
    const float sf = __expf(m - mn);
    m = mn;
    float rs = 0.f;
    u16 pb[4][4];
#pragma unroll
    for (int t = 0; t < 4; ++t)
#pragma unroll
      for (int r = 0; r < 4; ++r) {
        const float pv = __expf(s[t][r] - mn);
        rs += pv;
        pb[t][r] = f2bf(pv);
      }
    rs += __shfl_xor(rs, 16);
    rs += __shfl_xor(rs, 32);
    l = l * sf + rs;
#pragma unroll
    for (int t = 0; t < 4; ++t)
#pragma unroll
      for (int r = 0; r < 4; ++r) out[t][r] *= sf;

#pragma unroll
    for (int t = 0; t < 4; ++t) {
      uint2 pk;
      pk.x = (u32)pb[t][0] | ((u32)pb[t][1] << 16);
      pk.y = (u32)pb[t][2] | ((u32)pb[t][3] << 16);
      *(uint2*)((char*)Pw + SWB(q, t * 32 + g * 8)) = pk;
    }

#pragma unroll
    for (int c = 0; c < 2; ++c) {
      const bf16x8 pf = *(const bf16x8*)((char*)Pw + SWB(q, c * 64 + g * 16));
#pragma unroll
      for (int t = 0; t < 4; ++t) {
        const bf16x8 vf = *(const bf16x8*)((char*)Vs[cur] + SWB(t * 16 + q, c * 64 + g * 16));
        out[t] = __builtin_amdgcn_mfma_f32_16x16x32_bf16(vf, pf, out[t], 0, 0, 0);
      }
    }
    __builtin_amdgcn_sched_barrier(0);
    __builtin_amdgcn_s_barrier();
    __builtin_amdgcn_sched_barrier(0);
    cur ^= 1;
  }

  const float inv = 1.f / l;
  u16* arow = att + ((long)(b * 1024 + q0 + w * 16 + q)) * 768 + hh * 64;
#pragma unroll
  for (int t = 0; t < 4; ++t) {
    uint2 pk;
    pk.x = (u32)f2bf(out[t][0] * inv) | ((u32)f2bf(out[t][1] * inv) << 16);
    pk.y = (u32)f2bf(out[t][2] * inv) | ((u32)f2bf(out[t][3] * inv) << 16);
    *(uint2*)(arow + t * 16 + g * 4) = pk;
  }
}

// ---------------- per-layer pipelined GEMM: 2-phase/K-tile, counted vmcnt ----
// A-dbuf + B-triple-buf. Steady queue at ph1: [B(t)BC, A(t)AC, B(t+1)BC]
// -> vmcnt(BCALLS) lands B(t)+A(t); last tile vmcnt(0).
template <int BM, int BN, int TH>
__global__ __launch_bounds__(TH, 2) void gemmP(
    const u16* __restrict__ A, const u16* __restrict__ Wt,
    const float* __restrict__ bias, const float* resid,
    float* outF, u16* outB,
    int K, int lda, int ldw, int ldc,
    int Nreal, float scale, int scale_ncols, int relu) {
  constexpr int WN = TH / 128;               // 512->4, 256->2 (WM=2 always)
  constexpr int FM = BM / 32;
  constexpr int FN = BN / (WN * 16);
  constexpr int ACALLS = (BM * 128) / (TH * 16);
  constexpr int BCALLS = (BN * 128) / (TH * 16);

  __shared__ u16 As[2][BM * 64];
  __shared__ u16 Bs[3][BN * 64];

  const int tid = threadIdx.x;
  const int lane = tid & 63;
  const int wid = tid >> 6;
  const int wm = wid / WN, wn = wid % WN;
  const int lrow = lane & 15, kgrp = lane >> 4;

  const long row0 = (long)blockIdx.y * BM;
  const long col0 = (long)blockIdx.x * BN;

  f32x4 acc[FM][FN];
#pragma unroll
  for (int m = 0; m < FM; ++m)
#pragma unroll
    for (int n = 0; n < FN; ++n) acc[m][n] = (f32x4){0.f, 0.f, 0.f, 0.f};

  auto stageA = [&](int buf, int k0, int c) {
    const int o = c * (TH * 16) + tid * 16;
    const int r = o >> 7, cb = o & 127;
    const int cbs = cb ^ ((r & 7) << 4);
    load_lds16(A + (row0 + r) * lda + k0 + (cbs >> 1), (char*)As[buf] + o);
  };
  auto stageB = [&](int buf, int k0, int c) {
    const int o = c * (TH * 16) + tid * 16;
    const int r = o >> 7, cb = o & 127;
    const int cbs = cb ^ ((r & 7) << 4);
    load_lds16(Wt + (col0 + r) * ldw + k0 + (cbs >> 1), (char*)Bs[buf] + o);
  };

  const int T = K >> 6;   // requires T >= 3
#pragma unroll
  for (int c = 0; c < BCALLS; ++c) stageB(0, 0, c);
#pragma unroll
  for (int c = 0; c < ACALLS; ++c) stageA(0, 0, c);
#pragma unroll
  for (int c = 0; c < BCALLS; ++c) stageB(1, 64, c);

  for (int t = 0; t < T; ++t) {
    const int cura = t & 1, nxta = cura ^ 1;
    const int curb = t % 3, nxtb = (t + 2) % 3;
    const int k1 = (t + 1) << 6;
    const int k2 = (t + 2) << 6;
    bf16x8 af[FM], bfr[FN];

    // ---------- phase 1: kk0 ----------
    if (t == T - 1) waitv<0>(); else waitv<BCALLS>();
    __builtin_amdgcn_sched_barrier(0);
    __builtin_amdgcn_s_barrier();
    __builtin_amdgcn_sched_barrier(0);
#pragma unroll
    for (int m = 0; m < FM; ++m)
      af[m] = *(const bf16x8*)((char*)As[cura] + SWB(wm * FM * 16 + m * 16 + lrow, kgrp * 16));
#pragma unroll
    for (int n = 0; n < FN; ++n)
      bfr[n] = *(const bf16x8*)((char*)Bs[curb] + SWB(wn * FN * 16 + n * 16 + lrow, kgrp * 16));
    if (t + 1 < T) {
#pragma unroll
      for (int c = 0; c < ACALLS; ++c) stageA(nxta, k1, c);
    }
    asm volatile("s_waitcnt lgkmcnt(0)" ::: "memory");
    __builtin_amdgcn_sched_barrier(0);
    __builtin_amdgcn_s_setprio(1);
#pragma unroll
    for (int m = 0; m < FM; ++m)
#pragma unroll
      for (int n = 0; n < FN; ++n)
        acc[m][n] = __builtin_amdgcn_mfma_f32_16x16x32_bf16(af[m], bfr[n], acc[m][n], 0, 0, 0);
    __builtin_amdgcn_s_setprio(0);

    // ---------- phase 2: kk1 ----------
    __builtin_amdgcn_s_barrier();
    __builtin_amdgcn_sched_barrier(0);
#pragma unroll
    for (int m = 0; m < FM; ++m)
      af[m] = *(const bf16x8*)((char*)As[cura] + SWB(wm * FM * 16 + m * 16 + lrow, 64 + kgrp * 16));
#pragma unroll
    for (int n = 0; n < FN; ++n)
      bfr[n] = *(const bf16x8*)((char*)Bs[curb] + SWB(wn * FN * 16 + n * 16 + lrow, 64 + kgrp * 16));
    if (t + 2 < T) {
#pragma unroll
      for (int c = 0; c < BCALLS; ++c) stageB(nxtb, k2, c);
    }
    asm volatile("s_waitcnt lgkmcnt(0)" ::: "memory");
    __builtin_amdgcn_sched_barrier(0);
    __builtin_amdgcn_s_setprio(1);
#pragma unroll
    for (int m = 0; m < FM; ++m)
#pragma unroll
      for (int n = 0; n < FN; ++n)
        acc[m][n] = __builtin_amdgcn_mfma_f32_16x16x32_bf16(af[m], bfr[n], acc[m][n], 0, 0, 0);
    __builtin_amdgcn_s_setprio(0);
  }

#pragma unroll
  for (int m = 0; m < FM; ++m) {
    const long row = row0 + wm * FM * 16 + m * 16 + kgrp * 4;
#pragma unroll
    for (int n = 0; n < FN; ++n) {
      const long col = col0 + wn * FN * 16 + n * 16 + lrow;
      if (col < Nreal) {
        const float bb = bias ? bias[col] : 0.f;
        const float sc = (col < scale_ncols) ? scale : 1.f;
#pragma unroll
        for (int r = 0; r < 4; ++r) {
          const long idx = (row + r) * ldc + col;
          float v = (acc[m][n][r] + bb) * sc;
          if (resid) v += resid[idx];
          if (relu) v = fmaxf(v, 0.f);
          if (outF) outF[idx] = v;
          else outB[idx] = f2bf(v);
        }
      }
    }
  }
}

// ---------------- vocab GEMM: 256x256, 8 waves, 4-phase, A-dbuf + B-TRIPLE-buf ----
__global__ __launch_bounds__(512, 1) void gemm8_vocab(
    const u16* __restrict__ A, const u16* __restrict__ Wt,
    const float* __restrict__ bias, float* __restrict__ outF,
    int K, int lda, int ldw, int ldc, int Nreal) {
  __shared__ u16 As[2][256 * 64];
  __shared__ u16 Bs[3][256 * 64];

  const int tid = threadIdx.x;
  const int lane = tid & 63;
  const int wid = tid >> 6;
  const int wm = wid >> 2, wn = wid & 3;
  const int lrow = lane & 15, kgrp = lane >> 4;

  const int flat = blockIdx.x;
  const int g = flat >> 7, rem = flat & 127;
  const int fullg = gridDim.x >> 7;
  int panel, rb;
  if (g < fullg) { panel = g * 16 + (rem & 15); rb = rem >> 4; }
  else           { panel = fullg * 16 + (rem >> 3); rb = rem & 7; }
  const long row0 = (long)rb * 256;
  const long col0 = (long)panel * 256;

  f32x4 acc[8][4];
#pragma unroll
  for (int m = 0; m < 8; ++m)
#pragma unroll
    for (int n = 0; n < 4; ++n) acc[m][n] = (f32x4){0.f, 0.f, 0.f, 0.f};

  auto stageA = [&](int buf, int k0, int c) {
    const int o = c * 8192 + tid * 16;
    const int r = o >> 7, cb = o & 127;
    const int cbs = cb ^ ((r & 7) << 4);
    load_lds16(A + (row0 + r) * lda + k0 + (cbs >> 1), (char*)As[buf] + o);
  };
  auto stageB = [&](int buf, int k0, int c) {
    const int o = c * 8192 + tid * 16;
    const int r = o >> 7, cb = o & 127;
    const int cbs = cb ^ ((r & 7) << 4);
    load_lds16(Wt + (col0 + r) * ldw + k0 + (cbs >> 1), (char*)Bs[buf] + o);
  };

  const int T = K >> 6;
  stageB(0, 0, 0); stageB(0, 0, 1); stageB(0, 0, 2); stageB(0, 0, 3);
  stageA(0, 0, 0); stageA(0, 0, 2); stageA(0, 0, 1); stageA(0, 0, 3);
  stageB(1, 64, 0); stageB(1, 64, 1); stageB(1, 64, 2); stageB(1, 64, 3);

  for (int t = 0; t < T; ++t) {
    const int cura = t & 1, nxta = cura ^ 1;
    const int curb = t % 3, nxtb = (t + 2) % 3;
    const int k1 = (t + 1) << 6;
    const int k2 = (t + 2) << 6;
    const bool pfA = (t + 1 < T);
    const bool pfB = (t + 2 < T);
    const bool last = (t == T - 1);
    bf16x8 am[4], bn0[4];

    // ---------- phase 1: kk0, m0-3 ----------
    if (last) waitv<2>(); else waitv<6>();
    __builtin_amdgcn_sched_barrier(0);
    __builtin_amdgcn_s_barrier();
    __builtin_amdgcn_sched_barrier(0);
#pragma unroll
    for (int m = 0; m < 4; ++m)
      am[m] = *(const bf16x8*)((char*)As[cura] + SWB(wm * 128 + m * 16 + lrow, kgrp * 16));
#pragma unroll
    for (int n = 0; n < 4; ++n)
      bn0[n] = *(const bf16x8*)((char*)Bs[curb] + SWB(wn * 64 + n * 16 + lrow, kgrp * 16));
    if (pfA) { stageA(nxta, k1, 0); stageA(nxta, k1, 2); }
    asm volatile("s_waitcnt lgkmcnt(0)" ::: "memory");
    __builtin_amdgcn_sched_barrier(0);
    __builtin_amdgcn_s_setprio(1);
#pragma unroll
    for (int m = 0; m < 4; ++m)
#pragma unroll
      for (int n = 0; n < 4; ++n)
        acc[m][n] = __builtin_amdgcn_mfma_f32_16x16x32_bf16(am[m], bn0[n], acc[m][n], 0, 0, 0);
    __builtin_amdgcn_s_setprio(0);

    // ---------- phase 2: kk0, m4-7 ----------
    if (last) waitv<0>(); else waitv<6>();
    __builtin_amdgcn_sched_barrier(0);
    __builtin_amdgcn_s_barrier();
    __builtin_amdgcn_sched_barrier(0);
#pragma unroll
    for (int m = 0; m < 4; ++m)
      am[m] = *(const bf16x8*)((char*)As[cura] + SWB(wm * 128 + (m + 4) * 16 + lrow, kgrp * 16));
    if (pfA) { stageA(nxta, k1, 1); stageA(nxta, k1, 3); }
    asm volatile("s_waitcnt lgkmcnt(0)" ::: "memory");
    __builtin_amdgcn_sched_barrier(0);
    __builtin_amdgcn_s_setprio(1);
#pragma unroll
    for (int m = 0; m < 4; ++m)
#pragma unroll
      for (int n = 0; n < 4; ++n)
        acc[m + 4][n] = __builtin_amdgcn_mfma_f32_16x16x32_bf16(am[m], bn0[n], acc[m + 4][n], 0, 0, 0);
    __builtin_amdgcn_s_setprio(0);

    // ---------- phase 3: kk1, m0-3 ----------
    __builtin_amdgcn_s_barrier();
    __builtin_amdgcn_sched_barrier(0);
#pragma unroll
    for (int m = 0; m < 4; ++m)
      am[m] = *(const bf16x8*)((char*)As[cura] + SWB(wm * 128 + m * 16 + lrow, 64 + kgrp * 16));
#pragma unroll
    for (int n = 0; n < 4; ++n)
      bn0[n] = *(const bf16x8*)((char*)Bs[curb] + SWB(wn * 64 + n * 16 + lrow, 64 + kgrp * 16));
    if (pfB) { stageB(nxtb, k2, 0); stageB(nxtb, k2, 1); }
    asm volatile("s_waitcnt lgkmcnt(0)" ::: "memory");
    __builtin_amdgcn_sched_barrier(0);
    __builtin_amdgcn_s_setprio(1);
#pragma unroll
    for (int m = 0; m < 4; ++m)
#pragma unroll
      for (int n = 0; n < 4; ++n)
        acc[m][n] = __builtin_amdgcn_mfma_f32_16x16x32_bf16(am[m], bn0[n], acc[m][n], 0, 0, 0);
    __builtin_amdgcn_s_setprio(0);

    // ---------- phase 4: kk1, m4-7 ----------
    __builtin_amdgcn_s_barrier();
    __builtin_amdgcn_sched_barrier(0);
#pragma unroll
    for (int m = 0; m < 4; ++m)
      am[m] = *(const bf16x8*)((char*)As[cura] + SWB(wm * 128 + (m + 4) * 16 + lrow, 64 + kgrp * 16));
    if (pfB) { stageB(nxtb, k2, 2); stageB(nxtb, k2, 3); }
    asm volatile("s_waitcnt lgkmcnt(0)" ::: "memory");
    __builtin_amdgcn_sched_barrier(0);
    __builtin_amdgcn_s_setprio(1);
#pragma unroll
    for (int m = 0; m < 4; ++m)
#pragma unroll
      for (int n = 0; n < 4; ++n)
        acc[m + 4][n] = __builtin_amdgcn_mfma_f32_16x16x32_bf16(am[m], bn0[n], acc[m + 4][n], 0, 0, 0);
    __builtin_amdgcn_s_setprio(0);
    __builtin_amdgcn_s_barrier();
  }

#pragma unroll
  for (int m = 0; m < 8; ++m) {
    const long row = row0 + wm * 128 + m * 16 + kgrp * 4;
#pragma unroll
    for (int n = 0; n < 4; ++n) {
      const long col = col0 + wn * 64 + n * 16 + lrow;
      if (col < Nreal) {
        const float bb = bias[col];
#pragma unroll
        for (int r = 0; r < 4; ++r)
          outF[(row + r) * ldc + col] = acc[m][n][r] + bb;
      }
    }
  }
}

extern "C" void kernel_launch(void* const* d_in, const int* in_sizes, int n_in,
                              void* d_out, int out_size, void* d_ws, size_t ws_size,
                              hipStream_t stream) {
  const int* x = (const int*)d_in[0];
  const float* tok_emb = (const float*)d_in[1];
  const float* Wq = (const float*)d_in[2];
  const float* bq = (const float*)d_in[3];
  const float* Wk = (const float*)d_in[4];
  const float* bk = (const float*)d_in[5];
  const float* Wv = (const float*)d_in[6];
  const float* bv = (const float*)d_in[7];
  const float* Wo = (const float*)d_in[8];
  const float* bo = (const float*)d_in[9];
  const float* ln1g = (const float*)d_in[10];
  const float* ln1b = (const float*)d_in[11];
  const float* ln2g = (const float*)d_in[12];
  const float* ln2b = (const float*)d_in[13];
  const float* W1 = (const float*)d_in[14];
  const float* b1 = (const float*)d_in[15];
  const float* W2 = (const float*)d_in[16];
  const float* b2 = (const float*)d_in[17];
  const float* lnfg = (const float*)d_in[18];
  const float* lnfb = (const float*)d_in[19];
  const float* Wout = (const float*)d_in[20];
  const float* bout = (const float*)d_in[21];

  char* p = (char*)d_ws;
  auto alloc = [&](size_t bytes) {
    void* r = (void*)p;
    p += (bytes + 255) & ~(size_t)255;
    return r;
  };
  float* h = (float*)alloc(2048L * 768 * 4);
  u16* y = (u16*)alloc(2048L * 768 * 2);
  u16* qkv = (u16*)alloc(2048L * 2304 * 2);
  u16* v_t = (u16*)alloc(2L * 768 * 1024 * 2);
  u16* att = (u16*)alloc(2048L * 768 * 2);
  u16* mid = (u16*)alloc(2048L * 3072 * 2);
  u16* wout_t = (u16*)alloc(50432L * 768 * 2);
  float* bqkv_all = (float*)alloc(12L * 2304 * 4);

  // converted per-layer weights live in d_out (fully overwritten by vocab GEMM)
  u16* wbase = (u16*)d_out;

  const dim3 tb(256);
  const dim3 cb(32, 8);

  embed_kernel<<<2048, tb, 0, stream>>>(x, tok_emb, h);
  bias_all<<<108, tb, 0, stream>>>(bq, bk, bv, bqkv_all);
  conv_transpose<<<dim3(1576, 24), cb, 0, stream>>>(Wout, wout_t, 768, 50257, 50432);
  conv_layers<<<dim3(6912, 12), cb, 0, stream>>>(Wq, Wk, Wv, Wo, W1, W2, wbase);

  for (int l = 0; l < 12; ++l) {
    u16* wl = wbase + (long)l * 7077888;
    u16* qkvt_l = wl;
    u16* wot_l = wl + 1769472;
    u16* w1t_l = wot_l + 589824;
    u16* w2t_l = w1t_l + 2359296;

    ln_kernel<<<2048, tb, 0, stream>>>(h, ln1g + l * 768, ln1b + l * 768, y);

    // fused QKV: qkv = (y @ [Wq|Wk|Wv] + bqkv), q cols scaled 1/8 (128x128 tiles)
    gemmP<128, 128, 512><<<dim3(18, 16), dim3(512), 0, stream>>>(
        y, qkvt_l, bqkv_all + l * 2304, nullptr, nullptr, qkv,
        768, 768, 768, 2304, 2304, 0.125f, 768, 0);

    transpose_v<<<dim3(24, 32, 2), cb, 0, stream>>>(qkv, v_t);

    flash_attn<<<dim3(384), tb, 0, stream>>>(qkv, v_t, att);

    // h += att @ Wo + bo
    gemmP<64, 64, 256><<<dim3(12, 32), tb, 0, stream>>>(
        att, wot_l, bo + l * 768, h, h, nullptr,
        768, 768, 768, 768, 768, 1.f, 0, 0);

    ln_kernel<<<2048, tb, 0, stream>>>(h, ln2g + l * 768, ln2b + l * 768, y);

    // mid = relu(y @ W1 + b1)  (128x128 tiles)
    gemmP<128, 128, 512><<<dim3(24, 16), dim3(512), 0, stream>>>(
        y, w1t_l, b1 + l * 3072, nullptr, nullptr, mid,
        768, 768, 768, 3072, 3072, 1.f, 0, 1);

    // h += mid @ W2 + b2
    gemmP<64, 64, 256><<<dim3(12, 32), tb, 0, stream>>>(
        mid, w2t_l, b2 + l * 768, h, h, nullptr,
        3072, 3072, 3072, 768, 768, 1.f, 0, 0);
  }

  ln_kernel<<<2048, tb, 0, stream>>>(h, lnfg, lnfb, y);

  // logits = y @ Wout + bout — 4-phase 256x256, A-dbuf + B-triple-buf
  gemm8_vocab<<<dim3(1576), dim3(512), 0, stream>>>(
      y, wout_t, bout, (float*)d_out, 768, 768, 768, 50257, 50257);
}